// Round 5
// baseline (54.930 us; speedup 1.0000x reference)
//
#include <hip/hip_runtime.h>

namespace {

constexpr int F   = 128;
constexpr int L   = 4096;
constexpr int Bsz = 32;
constexpr int TR  = 128;   // output rows per block
constexpr int NT  = 4;     // n-tiles of 16 per block (64 cols)

using short8 = __attribute__((ext_vector_type(8))) short;
using f32x4  = __attribute__((ext_vector_type(4))) float;
using u32x4  = __attribute__((ext_vector_type(4))) unsigned int;

__device__ inline unsigned short f2bf(float x) {
    unsigned u = __builtin_bit_cast(unsigned, x);
    unsigned r = (u + 0x7fffu + ((u >> 16) & 1u)) >> 16;
    return (unsigned short)r;
}

__device__ inline unsigned pack2(float lo, float hi) {
    return (unsigned)f2bf(lo) | ((unsigned)f2bf(hi) << 16);
}

// Head-folded weights in MFMA-A-fragment order (one (s,tn) fragment read is
// 64 CONSECUTIVE 16B chunks -> lane-linear, conflict-free):
//   bf16 idx: j = idx&7, chunk c2 = idx>>3
//   l15 = c2&15, g = (c2>>4)&3, tn = (c2>>6)&7, s = c2>>9
//   n = tn*16 + l15,  k = (s*4+g)*8 + j
//   k<128: mean_h W_src[(h*128+n)*128+k]; k>=128: mean_h W_res[...][k-128]
__global__ void prep(const float* __restrict__ Wsrc,
                     const float* __restrict__ Wres,
                     const float* __restrict__ bias,
                     unsigned short* __restrict__ Wf,
                     float* __restrict__ bbar)
{
    int idx = blockIdx.x * 256 + threadIdx.x;
    if (idx < 2 * F * F) {
        int j   = idx & 7;
        int c2  = idx >> 3;
        int l15 = c2 & 15;
        int g   = (c2 >> 4) & 3;
        int tn  = (c2 >> 6) & 7;
        int s   = c2 >> 9;
        int n   = tn * 16 + l15;
        int k   = (s * 4 + g) * 8 + j;
        int e   = k & (F - 1);
        const float* W = (k < F) ? Wsrc : Wres;
        float sum = 0.f;
#pragma unroll
        for (int h = 0; h < 8; ++h) sum += W[(h * F + n) * F + e];
        Wf[idx] = f2bf(sum * 0.125f);
    }
    if (idx < F) {
        float s = 0.f;
#pragma unroll
        for (int h = 0; h < 8; ++h) s += bias[h * F + idx];
        bbar[idx] = s * 0.125f;
    }
}

__device__ inline short8 cvt8(float4 a, float4 b) {
    u32x4 u;
    u[0] = pack2(a.x, a.y);
    u[1] = pack2(a.z, a.w);
    u[2] = pack2(b.x, b.y);
    u[3] = pack2(b.z, b.w);
    return __builtin_bit_cast(short8, u);
}

__global__ __launch_bounds__(512, 4)
void gat_mfma(const float* __restrict__ loc,
              const unsigned short* __restrict__ Wf,
              const float* __restrict__ bbar,
              float* __restrict__ out)
{
    extern __shared__ char smem[];   // 32 KB: this block's 64-col W slice

    const int b    = blockIdx.y;
    const int tile = blockIdx.x >> 1;
    const int half = blockIdx.x & 1;       // which 64-col slice
    const int p0   = tile * TR;
    const int t    = threadIdx.x;
    const int lane = t & 63;
    const int w    = t >> 6;
    const int g    = lane >> 4;
    const int l15  = lane & 15;
    const float* locb = loc + (size_t)b * L * F;

    // ---- A: direct global->reg loads (issue first, in flight over B stage)
    const int prow  = p0 + w * 16 + l15;   // this lane's output row
    const int pprev = prow - 1;
    const float* apb = locb + (size_t)((pprev < 0) ? 0 : pprev) * F + g * 8;
    const float* acb = locb + (size_t)prow * F + g * 8;
    float4 ap[8], ac[8];
#pragma unroll
    for (int s = 0; s < 4; ++s) {
        ap[s * 2]     = *(const float4*)(apb + s * 32);
        ap[s * 2 + 1] = *(const float4*)(apb + s * 32 + 4);
        ac[s * 2]     = *(const float4*)(acb + s * 32);
        ac[s * 2 + 1] = *(const float4*)(acb + s * 32 + 4);
    }

    // ---- B: 32 KB global->LDS async.
    // flat chunk index within this half: flat = i*512 + t; per wave the 64
    // source chunks are consecutive (rest = lane) -> coalesced 1KB segments.
#pragma unroll
    for (int i = 0; i < 4; ++i) {
        int sw  = i * 8 + w;           // s*4 + tnh
        int s   = sw >> 2;
        int tnh = sw & 3;
        int srcChunk = (s << 9) + ((half * NT + tnh) << 6) + lane;
        __builtin_amdgcn_global_load_lds(
            (const __attribute__((address_space(1))) void*)((const char*)Wf + (size_t)srcChunk * 16),
            (__attribute__((address_space(3))) void*)(smem + (i * 512 + (t & ~63)) * 16),
            16, 0, 0);
    }

    if (pprev < 0) {
#pragma unroll
        for (int i = 0; i < 8; ++i) ap[i] = make_float4(0.f, 0.f, 0.f, 0.f);
    }

    // convert A to bf16 fragments while B stage completes
    short8 afr[8];
#pragma unroll
    for (int s = 0; s < 4; ++s) {
        afr[s]     = cvt8(ap[s * 2], ap[s * 2 + 1]);
        afr[s + 4] = cvt8(ac[s * 2], ac[s * 2 + 1]);
    }

    __syncthreads();

    f32x4 acc[NT];
#pragma unroll
    for (int i = 0; i < NT; ++i) { acc[i][0] = 0.f; acc[i][1] = 0.f; acc[i][2] = 0.f; acc[i][3] = 0.f; }

    const char* bs_base = (const char*)smem + lane * 16;
#pragma unroll
    for (int s = 0; s < 8; ++s) {
#pragma unroll
        for (int tn = 0; tn < NT; ++tn) {
            short8 wfrag = *(const short8*)(bs_base + ((s * NT + tn) << 10));
            acc[tn] = __builtin_amdgcn_mfma_f32_16x16x32_bf16(wfrag, afr[s], acc[tn], 0, 0, 0);
        }
    }

    // ---- epilogue: lane holds cols (half*64 + tn*16 + g*4 + r) of row `prow`
    float* outr = out + (size_t)b * L * F + (size_t)prow * F;
    const int colb = half * 64 + g * 4;
#pragma unroll
    for (int tn = 0; tn < NT; ++tn) {
        int col = colb + tn * 16;
        float4 bb = *(const float4*)(bbar + col);
        float4 v = make_float4(acc[tn][0] + bb.x, acc[tn][1] + bb.y,
                               acc[tn][2] + bb.z, acc[tn][3] + bb.w);
        if (prow == 0) v = *(const float4*)(locb + col);   // out[b,0,:] = loc[b,0,:]
        *(float4*)(outr + col) = v;
    }
}

} // namespace

extern "C" void kernel_launch(void* const* d_in, const int* in_sizes, int n_in,
                              void* d_out, int out_size, void* d_ws, size_t ws_size,
                              hipStream_t stream) {
    const float* loc  = (const float*)d_in[0];
    const float* Wsrc = (const float*)d_in[1];
    // d_in[2] W_dst, d_in[3] attn_l, d_in[4] attn_r cancel (alpha == 1)
    const float* Wres = (const float*)d_in[5];
    const float* bias = (const float*)d_in[6];

    unsigned short* Wf   = (unsigned short*)d_ws;          // 32768 bf16 = 64 KB
    float*          bbar = (float*)((char*)d_ws + 2 * F * F * 2);
    float*          outp = (float*)d_out;

    prep<<<128, 256, 0, stream>>>(Wsrc, Wres, bias, Wf, bbar);

    gat_mfma<<<dim3(2 * (L / TR), Bsz), 512, 32768, stream>>>(loc, Wf, bbar, outp);
}

// Round 6
// 51.476 us; speedup vs baseline: 1.0671x; 1.0671x over previous
//
#include <hip/hip_runtime.h>

namespace {

constexpr int F     = 128;
constexpr int L     = 4096;
constexpr int Bsz   = 32;
constexpr int TR    = 128;   // rows per tile-step
constexpr int NITER = 2;     // tile-steps per block
constexpr int NT    = 8;     // n-tiles of 16 (128 cols)

using short8 = __attribute__((ext_vector_type(8))) short;
using f32x4  = __attribute__((ext_vector_type(4))) float;
using u32x4  = __attribute__((ext_vector_type(4))) unsigned int;

__device__ inline unsigned short f2bf(float x) {
    unsigned u = __builtin_bit_cast(unsigned, x);
    unsigned r = (u + 0x7fffu + ((u >> 16) & 1u)) >> 16;
    return (unsigned short)r;
}

__device__ inline unsigned pack2(float lo, float hi) {
    return (unsigned)f2bf(lo) | ((unsigned)f2bf(hi) << 16);
}

__device__ inline short8 cvt8(float4 a, float4 b) {
    u32x4 u;
    u[0] = pack2(a.x, a.y);
    u[1] = pack2(a.z, a.w);
    u[2] = pack2(b.x, b.y);
    u[3] = pack2(b.z, b.w);
    return __builtin_bit_cast(short8, u);
}

// Head-folded weights in MFMA-A-fragment order (one (s,tn) fragment read is
// 64 CONSECUTIVE 16B chunks -> lane-linear, conflict-free):
//   bf16 idx: j = idx&7, chunk c2 = idx>>3
//   l15 = c2&15, g = (c2>>4)&3, tn = (c2>>6)&7, s = c2>>9
//   n = tn*16 + l15,  k = (s*4+g)*8 + j
//   k<128: mean_h W_src[(h*128+n)*128+k]; k>=128: mean_h W_res[...][k-128]
__global__ void prep(const float* __restrict__ Wsrc,
                     const float* __restrict__ Wres,
                     const float* __restrict__ bias,
                     unsigned short* __restrict__ Wf,
                     float* __restrict__ bbar)
{
    int idx = blockIdx.x * 256 + threadIdx.x;
    if (idx < 2 * F * F) {
        int j   = idx & 7;
        int c2  = idx >> 3;
        int l15 = c2 & 15;
        int g   = (c2 >> 4) & 3;
        int tn  = (c2 >> 6) & 7;
        int s   = c2 >> 9;
        int n   = tn * 16 + l15;
        int k   = (s * 4 + g) * 8 + j;
        int e   = k & (F - 1);
        const float* W = (k < F) ? Wsrc : Wres;
        float sum = 0.f;
#pragma unroll
        for (int h = 0; h < 8; ++h) sum += W[(h * F + n) * F + e];
        Wf[idx] = f2bf(sum * 0.125f);
    }
    if (idx < F) {
        float s = 0.f;
#pragma unroll
        for (int h = 0; h < 8; ++h) s += bias[h * F + idx];
        bbar[idx] = s * 0.125f;
    }
}

__global__ __launch_bounds__(512, 4)
void gat_mfma(const float* __restrict__ loc,
              const unsigned short* __restrict__ Wf,
              const float* __restrict__ bbar,
              float* __restrict__ out)
{
    extern __shared__ char smem[];   // 64 KB fragment-ordered weights

    const int b    = blockIdx.y;
    const int t    = threadIdx.x;
    const int lane = t & 63;
    const int w    = t >> 6;
    const int g    = lane >> 4;
    const int l15  = lane & 15;
    const float* locb = loc + (size_t)b * L * F;

    // ---- B: 64 KB global->LDS async, linear both sides (staged ONCE)
#pragma unroll
    for (int i = 0; i < 8; ++i) {
        int off = (i * 512 + t) * 16;
        __builtin_amdgcn_global_load_lds(
            (const __attribute__((address_space(1))) void*)((const char*)Wf + off),
            (__attribute__((address_space(3))) void*)(smem + (i * 512 + (t & ~63)) * 16),
            16, 0, 0);
    }

    const int rbase = blockIdx.x * (TR * NITER) + w * 16 + l15;
    const int coff  = g * 8;   // k-chunk column offset within a row

    // prologue: A loads for step 0 (prev rows -> P, cur rows -> C)
    float4 P[8], C[8];
    {
        int pr = (rbase > 0) ? rbase - 1 : 0;
        const float* pp = locb + (size_t)pr * F + coff;
        const float* cc = locb + (size_t)rbase * F + coff;
#pragma unroll
        for (int s = 0; s < 4; ++s) {
            P[s * 2]     = *(const float4*)(pp + s * 32);
            P[s * 2 + 1] = *(const float4*)(pp + s * 32 + 4);
            C[s * 2]     = *(const float4*)(cc + s * 32);
            C[s * 2 + 1] = *(const float4*)(cc + s * 32 + 4);
        }
    }

    __syncthreads();   // B ready (single barrier in the kernel)

    float* outb = out + (size_t)b * L * F;
    const char* bs_base = (const char*)smem + lane * 16;

#pragma unroll
    for (int it = 0; it < NITER; ++it) {
        const int prow = rbase + it * TR;

        f32x4 acc[NT];
#pragma unroll
        for (int i = 0; i < NT; ++i) { acc[i][0] = 0.f; acc[i][1] = 0.f; acc[i][2] = 0.f; acc[i][3] = 0.f; }

#pragma unroll
        for (int s = 0; s < 8; ++s) {
            short8 afr;
            if (s < 4) afr = cvt8(P[s * 2], P[s * 2 + 1]);
            else       afr = cvt8(C[(s - 4) * 2], C[(s - 4) * 2 + 1]);

            // refill buffers for the next tile-step as they go dead
            if (it + 1 < NITER && s == 3) {
                const float* pp = locb + (size_t)(prow + TR - 1) * F + coff;
#pragma unroll
                for (int q = 0; q < 4; ++q) {
                    P[q * 2]     = *(const float4*)(pp + q * 32);
                    P[q * 2 + 1] = *(const float4*)(pp + q * 32 + 4);
                }
            }
            if (it + 1 < NITER && s == 7) {
                const float* cc = locb + (size_t)(prow + TR) * F + coff;
#pragma unroll
                for (int q = 0; q < 4; ++q) {
                    C[q * 2]     = *(const float4*)(cc + q * 32);
                    C[q * 2 + 1] = *(const float4*)(cc + q * 32 + 4);
                }
            }

#pragma unroll
            for (int tn = 0; tn < NT; ++tn) {
                short8 wfrag = *(const short8*)(bs_base + ((s * NT + tn) << 10));
                acc[tn] = __builtin_amdgcn_mfma_f32_16x16x32_bf16(wfrag, afr, acc[tn], 0, 0, 0);
            }
        }

        // epilogue: lane holds cols (tn*16 + g*4 + r) of row `prow`
        float* outr = outb + (size_t)prow * F;
#pragma unroll
        for (int tn = 0; tn < NT; ++tn) {
            int col = tn * 16 + g * 4;
            float4 bb = *(const float4*)(bbar + col);
            float4 v = make_float4(acc[tn][0] + bb.x, acc[tn][1] + bb.y,
                                   acc[tn][2] + bb.z, acc[tn][3] + bb.w);
            if (prow == 0) v = *(const float4*)(locb + col);   // out[b,0,:] = loc[b,0,:]
            *(float4*)(outr + col) = v;
        }
    }
}

} // namespace

extern "C" void kernel_launch(void* const* d_in, const int* in_sizes, int n_in,
                              void* d_out, int out_size, void* d_ws, size_t ws_size,
                              hipStream_t stream) {
    const float* loc  = (const float*)d_in[0];
    const float* Wsrc = (const float*)d_in[1];
    // d_in[2] W_dst, d_in[3] attn_l, d_in[4] attn_r cancel (alpha == 1)
    const float* Wres = (const float*)d_in[5];
    const float* bias = (const float*)d_in[6];

    unsigned short* Wf   = (unsigned short*)d_ws;          // 32768 bf16 = 64 KB
    float*          bbar = (float*)((char*)d_ws + 2 * F * F * 2);
    float*          outp = (float*)d_out;

    prep<<<128, 256, 0, stream>>>(Wsrc, Wres, bias, Wf, bbar);

    gat_mfma<<<dim3(L / (TR * NITER), Bsz), 512, 65536, stream>>>(loc, Wf, bbar, outp);
}